// Round 4
// baseline (5568.796 us; speedup 1.0000x reference)
//
#include <hip/hip_runtime.h>

#define KCH 2
#define ZF 128   // Z == F == 128

// Native fp32 global atomic add on gfx9xx (avoids CAS-loop lowering).
__device__ inline void atomic_add_f32(float* p, float v) {
#if defined(__HIP_DEVICE_COMPILE__) && defined(__AMDGCN__)
  unsafeAtomicAdd(p, v);   // global_atomic_add_f32
#else
  atomicAdd(p, v);
#endif
}

// Zero d_out (it doubles as the SpMM accumulator). Harness poisons it 0xAA.
__global__ __launch_bounds__(256) void zero_kernel(float4* __restrict__ p, long long n4) {
  long long i = (long long)blockIdx.x * 256 + threadIdx.x;
  long long stride = (long long)gridDim.x * 256;
  for (; i < n4; i += stride) p[i] = make_float4(0.f, 0.f, 0.f, 0.f);
}

// Pass 1: tmp[k,row,:] += val * x[k,col,:]  (COO SpMM via fp32 atomics)
// One 64-lane wave per edge: lanes 0-31 handle k=0, lanes 32-63 handle k=1,
// each lane owns a float4 (4 of the 128 features) -> 512B coalesced gather.
__global__ __launch_bounds__(256) void scatter_spmm_kernel(
    const float* __restrict__ x,
    const int* __restrict__ rows,
    const int* __restrict__ cols,
    const float* __restrict__ vals,
    float* __restrict__ tmp, int E, int N) {
  int t = blockIdx.x * 256 + threadIdx.x;
  int e = t >> 6;
  if (e >= E) return;
  int sub = t & 63;
  int k = sub >> 5;
  int g = sub & 31;

  int row = rows[e];   // wave-uniform -> HW broadcast load
  int col = cols[e];
  float val = vals[e];

  const float4* src = (const float4*)(x + ((size_t)k * N + col) * ZF);
  float4 v = src[g];

  float* dst = tmp + ((size_t)k * N + row) * ZF + (size_t)g * 4;
  atomic_add_f32(dst + 0, val * v.x);
  atomic_add_f32(dst + 1, val * v.y);
  atomic_add_f32(dst + 2, val * v.z);
  atomic_add_f32(dst + 3, val * v.w);
}

// Pass 2: io[m,:] = relu(io[m,:] @ W) in place, 32 rows per block.
// LDS: W staged in two 64-row halves (32KB) + X tile (16KB) = 48KB < 64KB limit.
__global__ __launch_bounds__(256) void gemm_relu_inplace(
    float* __restrict__ io, const float* __restrict__ W, long long Mtotal) {
  __shared__ float Ws[64 * ZF];   // 32 KB (half of W)
  __shared__ float Xs[32 * ZF];   // 16 KB
  int tid = threadIdx.x;
  long long row0 = (long long)blockIdx.x * 32;

  // Stage X tile: 32 rows x 32 float4 = 1024 float4 / 256 threads = 4 iters.
  const float4* src = (const float4*)(io + row0 * ZF);
  float4* Xs4 = (float4*)Xs;
#pragma unroll
  for (int i = 0; i < 4; ++i) {
    int idx = tid + i * 256;
    long long r = row0 + (idx >> 5);
    Xs4[idx] = (r < Mtotal) ? src[idx] : make_float4(0.f, 0.f, 0.f, 0.f);
  }

  int f0 = (tid & 31) * 4;  // 32 f-groups of 4 consecutive features
  int rg = tid >> 5;        // 8 row-groups; rows rg + 8*j

  float acc[4][4];
#pragma unroll
  for (int j = 0; j < 4; ++j)
#pragma unroll
    for (int i = 0; i < 4; ++i) acc[j][i] = 0.f;

  const float4* W4 = (const float4*)W;
  float4* Ws4 = (float4*)Ws;

  for (int zh = 0; zh < 2; ++zh) {
    __syncthreads();  // zh=0: Xs staged; zh=1: compute done reading old Ws
    // Stage 64 rows of W: 64*32 = 2048 float4 / 256 threads = 8 iters.
#pragma unroll
    for (int i = 0; i < 8; ++i) {
      int idx = tid + i * 256;
      Ws4[idx] = W4[(size_t)zh * 2048 + idx];
    }
    __syncthreads();

#pragma unroll 4
    for (int z = 0; z < 64; ++z) {
      float4 wv = *(const float4*)(Ws + z * ZF + f0);   // ds_read_b128
#pragma unroll
      for (int j = 0; j < 4; ++j) {
        float xv = Xs[(rg + 8 * j) * ZF + (zh * 64 + z)];  // broadcast read
        acc[j][0] = fmaf(xv, wv.x, acc[j][0]);
        acc[j][1] = fmaf(xv, wv.y, acc[j][1]);
        acc[j][2] = fmaf(xv, wv.z, acc[j][2]);
        acc[j][3] = fmaf(xv, wv.w, acc[j][3]);
      }
    }
  }

#pragma unroll
  for (int j = 0; j < 4; ++j) {
    long long r = row0 + rg + 8 * j;
    if (r < Mtotal) {
      float4 o;
      o.x = fmaxf(acc[j][0], 0.f);
      o.y = fmaxf(acc[j][1], 0.f);
      o.z = fmaxf(acc[j][2], 0.f);
      o.w = fmaxf(acc[j][3], 0.f);
      *(float4*)(io + r * ZF + f0) = o;
    }
  }
}

extern "C" void kernel_launch(void* const* d_in, const int* in_sizes, int n_in,
                              void* d_out, int out_size, void* d_ws, size_t ws_size,
                              hipStream_t stream) {
  const float* x    = (const float*)d_in[0];   // [K, N, Z]
  const int*   rows = (const int*)d_in[1];     // [E]
  const int*   cols = (const int*)d_in[2];     // [E]
  const float* vals = (const float*)d_in[3];   // [E]
  const float* W    = (const float*)d_in[4];   // [Z, F]

  int E = in_sizes[1];
  int N = in_sizes[0] / (KCH * ZF);
  float* out = (float*)d_out;

  // Zero d_out (used as the SpMM accumulator; Z==F so sizes match).
  long long n4 = (long long)out_size / 4;
  int zblocks = (int)((n4 + 255) / 256);
  zero_kernel<<<zblocks, 256, 0, stream>>>((float4*)out, n4);

  long long total_threads = (long long)E * 64;
  int sblocks = (int)((total_threads + 255) / 256);
  scatter_spmm_kernel<<<sblocks, 256, 0, stream>>>(x, rows, cols, vals, out, E, N);

  long long Mtotal = (long long)KCH * N;
  int mblocks = (int)((Mtotal + 31) / 32);
  gemm_relu_inplace<<<mblocks, 256, 0, stream>>>(out, W, Mtotal);
}

// Round 5
// 672.295 us; speedup vs baseline: 8.2833x; 8.2833x over previous
//
#include <hip/hip_runtime.h>

#define KCH 2
#define ZF 128   // Z == F == 128
#define CHUNK 256

// ---------- small utility kernels for the counting sort ----------

__global__ __launch_bounds__(256) void zero_ints(int* __restrict__ p, int n) {
  int i = blockIdx.x * 256 + threadIdx.x;
  if (i < n) p[i] = 0;
}

__global__ __launch_bounds__(256) void hist_kernel(
    const int* __restrict__ rows, int* __restrict__ cnt, int E) {
  int i = blockIdx.x * 256 + threadIdx.x;
  if (i < E) atomicAdd(&cnt[rows[i]], 1);   // 400 KB counter array: L2-resident
}

// Per-chunk (256 counts) reduction -> chunk[b]
__global__ __launch_bounds__(256) void chunk_reduce(
    const int* __restrict__ cnt, int* __restrict__ chunk, int N) {
  __shared__ int s[256];
  int tid = threadIdx.x;
  int i = blockIdx.x * 256 + tid;
  s[tid] = (i < N) ? cnt[i] : 0;
  __syncthreads();
#pragma unroll
  for (int o = 128; o > 0; o >>= 1) {
    if (tid < o) s[tid] += s[tid + o];
    __syncthreads();
  }
  if (tid == 0) chunk[blockIdx.x] = s[0];
}

// Single block: exclusive scan of chunk sums (nch <= 512); also row_off[N]=E.
__global__ __launch_bounds__(512) void chunk_scan(
    int* __restrict__ chunk, int nch, int* __restrict__ row_off, int N, int E) {
  __shared__ int s[512];
  int tid = threadIdx.x;
  int v = (tid < nch) ? chunk[tid] : 0;
  s[tid] = v;
  __syncthreads();
#pragma unroll
  for (int o = 1; o < 512; o <<= 1) {
    int t = (tid >= o) ? s[tid - o] : 0;
    __syncthreads();
    s[tid] += t;
    __syncthreads();
  }
  if (tid < nch) chunk[tid] = s[tid] - v;   // exclusive
  if (tid == 0) row_off[N] = E;
}

// Exclusive scan within each 256-chunk, + chunk base -> row_off[i]
__global__ __launch_bounds__(256) void scan_within_chunk(
    const int* __restrict__ cnt, const int* __restrict__ chunk,
    int* __restrict__ row_off, int N) {
  __shared__ int s[256];
  int tid = threadIdx.x;
  int i = blockIdx.x * 256 + tid;
  int v = (i < N) ? cnt[i] : 0;
  s[tid] = v;
  __syncthreads();
#pragma unroll
  for (int o = 1; o < 256; o <<= 1) {
    int t = (tid >= o) ? s[tid - o] : 0;
    __syncthreads();
    s[tid] += t;
    __syncthreads();
  }
  if (i < N) row_off[i] = chunk[blockIdx.x] + s[tid] - v;
}

// Scatter edges into row-sorted order (atomics on 400 KB cursor: L2-resident).
__global__ __launch_bounds__(256) void bucket_kernel(
    const int* __restrict__ rows, const int* __restrict__ cols,
    const float* __restrict__ vals, const int* __restrict__ row_off,
    int* __restrict__ cursor, int* __restrict__ cols_s,
    float* __restrict__ vals_s, int E) {
  int i = blockIdx.x * 256 + threadIdx.x;
  if (i >= E) return;
  int r = rows[i];
  int p = row_off[r] + atomicAdd(&cursor[r], 1);
  cols_s[p] = cols[i];
  vals_s[p] = vals[i];
}

// ---------- CSR SpMM: one wave per row, both K channels, no atomics ----------
__global__ __launch_bounds__(256) void spmm_csr(
    const float* __restrict__ x, const int* __restrict__ row_off,
    const int* __restrict__ cols_s, const float* __restrict__ vals_s,
    float* __restrict__ out, int N) {
  int r = blockIdx.x * 4 + (threadIdx.x >> 6);
  int lane = threadIdx.x & 63;
  if (r >= N) return;
  int beg = row_off[r];
  int end = row_off[r + 1];
  size_t kstride = (size_t)N * ZF;

  float2 acc0 = make_float2(0.f, 0.f);
  float2 acc1 = make_float2(0.f, 0.f);
  for (int j = beg; j < end; ++j) {
    int c = cols_s[j];       // wave-uniform -> scalar load
    float v = vals_s[j];
    const float2* p0 = (const float2*)(x + (size_t)c * ZF);
    const float2* p1 = (const float2*)(x + kstride + (size_t)c * ZF);
    float2 a = p0[lane];     // 512 B coalesced gather
    float2 b = p1[lane];
    acc0.x = fmaf(v, a.x, acc0.x);
    acc0.y = fmaf(v, a.y, acc0.y);
    acc1.x = fmaf(v, b.x, acc1.x);
    acc1.y = fmaf(v, b.y, acc1.y);
  }
  ((float2*)(out + (size_t)r * ZF))[lane] = acc0;
  ((float2*)(out + kstride + (size_t)r * ZF))[lane] = acc1;
}

// ---------- fallback path (atomic scatter), used only if ws too small ----------
__device__ inline void atomic_add_f32(float* p, float v) {
#if defined(__HIP_DEVICE_COMPILE__) && defined(__AMDGCN__)
  unsafeAtomicAdd(p, v);
#else
  atomicAdd(p, v);
#endif
}

__global__ __launch_bounds__(256) void zero_kernel(float4* __restrict__ p, long long n4) {
  long long i = (long long)blockIdx.x * 256 + threadIdx.x;
  long long stride = (long long)gridDim.x * 256;
  for (; i < n4; i += stride) p[i] = make_float4(0.f, 0.f, 0.f, 0.f);
}

__global__ __launch_bounds__(256) void scatter_spmm_kernel(
    const float* __restrict__ x, const int* __restrict__ rows,
    const int* __restrict__ cols, const float* __restrict__ vals,
    float* __restrict__ tmp, int E, int N) {
  int t = blockIdx.x * 256 + threadIdx.x;
  int e = t >> 6;
  if (e >= E) return;
  int sub = t & 63;
  int k = sub >> 5;
  int g = sub & 31;
  int row = rows[e];
  int col = cols[e];
  float val = vals[e];
  const float4* src = (const float4*)(x + ((size_t)k * N + col) * ZF);
  float4 v = src[g];
  float* dst = tmp + ((size_t)k * N + row) * ZF + (size_t)g * 4;
  atomic_add_f32(dst + 0, val * v.x);
  atomic_add_f32(dst + 1, val * v.y);
  atomic_add_f32(dst + 2, val * v.z);
  atomic_add_f32(dst + 3, val * v.w);
}

// ---------- Pass 2: io[m,:] = relu(io[m,:] @ W) in place ----------
__global__ __launch_bounds__(256) void gemm_relu_inplace(
    float* __restrict__ io, const float* __restrict__ W, long long Mtotal) {
  __shared__ float Ws[64 * ZF];   // 32 KB (half of W)
  __shared__ float Xs[32 * ZF];   // 16 KB
  int tid = threadIdx.x;
  long long row0 = (long long)blockIdx.x * 32;

  const float4* src = (const float4*)(io + row0 * ZF);
  float4* Xs4 = (float4*)Xs;
#pragma unroll
  for (int i = 0; i < 4; ++i) {
    int idx = tid + i * 256;
    long long r = row0 + (idx >> 5);
    Xs4[idx] = (r < Mtotal) ? src[idx] : make_float4(0.f, 0.f, 0.f, 0.f);
  }

  int f0 = (tid & 31) * 4;
  int rg = tid >> 5;

  float acc[4][4];
#pragma unroll
  for (int j = 0; j < 4; ++j)
#pragma unroll
    for (int i = 0; i < 4; ++i) acc[j][i] = 0.f;

  const float4* W4 = (const float4*)W;
  float4* Ws4 = (float4*)Ws;

  for (int zh = 0; zh < 2; ++zh) {
    __syncthreads();
#pragma unroll
    for (int i = 0; i < 8; ++i) {
      int idx = tid + i * 256;
      Ws4[idx] = W4[(size_t)zh * 2048 + idx];
    }
    __syncthreads();

#pragma unroll 4
    for (int z = 0; z < 64; ++z) {
      float4 wv = *(const float4*)(Ws + z * ZF + f0);
#pragma unroll
      for (int j = 0; j < 4; ++j) {
        float xv = Xs[(rg + 8 * j) * ZF + (zh * 64 + z)];
        acc[j][0] = fmaf(xv, wv.x, acc[j][0]);
        acc[j][1] = fmaf(xv, wv.y, acc[j][1]);
        acc[j][2] = fmaf(xv, wv.z, acc[j][2]);
        acc[j][3] = fmaf(xv, wv.w, acc[j][3]);
      }
    }
  }

#pragma unroll
  for (int j = 0; j < 4; ++j) {
    long long r = row0 + rg + 8 * j;
    if (r < Mtotal) {
      float4 o;
      o.x = fmaxf(acc[j][0], 0.f);
      o.y = fmaxf(acc[j][1], 0.f);
      o.z = fmaxf(acc[j][2], 0.f);
      o.w = fmaxf(acc[j][3], 0.f);
      *(float4*)(io + r * ZF + f0) = o;
    }
  }
}

extern "C" void kernel_launch(void* const* d_in, const int* in_sizes, int n_in,
                              void* d_out, int out_size, void* d_ws, size_t ws_size,
                              hipStream_t stream) {
  const float* x    = (const float*)d_in[0];   // [K, N, Z]
  const int*   rows = (const int*)d_in[1];     // [E]
  const int*   cols = (const int*)d_in[2];     // [E]
  const float* vals = (const float*)d_in[3];   // [E]
  const float* W    = (const float*)d_in[4];   // [Z, F]

  int E = in_sizes[1];
  int N = in_sizes[0] / (KCH * ZF);
  float* out = (float*)d_out;

  int nch = (N + CHUNK - 1) / CHUNK;           // 391 for N=100k (must be <= 512)

  // ws carve-up (16B-aligned blocks)
  size_t off = 0;
  auto carve = [&](size_t bytes) {
    size_t p = off;
    off += (bytes + 15) & ~(size_t)15;
    return (char*)d_ws + p;
  };
  int*   row_off = (int*)carve((size_t)(N + 1) * 4);
  int*   cursor  = (int*)carve((size_t)N * 4);
  int*   chunk   = (int*)carve((size_t)nch * 4);
  int*   cols_s  = (int*)carve((size_t)E * 4);
  float* vals_s  = (float*)carve((size_t)E * 4);
  bool ws_ok = (off <= ws_size) && (nch <= 512);

  if (ws_ok) {
    int nb_N = (N + 255) / 256;
    int nb_E = (E + 255) / 256;

    zero_ints<<<nb_N, 256, 0, stream>>>(cursor, N);
    hist_kernel<<<nb_E, 256, 0, stream>>>(rows, cursor, E);
    chunk_reduce<<<nch, 256, 0, stream>>>(cursor, chunk, N);
    chunk_scan<<<1, 512, 0, stream>>>(chunk, nch, row_off, N, E);
    scan_within_chunk<<<nch, 256, 0, stream>>>(cursor, chunk, row_off, N);
    zero_ints<<<nb_N, 256, 0, stream>>>(cursor, N);
    bucket_kernel<<<nb_E, 256, 0, stream>>>(rows, cols, vals, row_off, cursor,
                                            cols_s, vals_s, E);
    // CSR SpMM writes every output row exactly once -> no d_out zeroing needed.
    int sblocks = (N + 3) / 4;
    spmm_csr<<<sblocks, 256, 0, stream>>>(x, row_off, cols_s, vals_s, out, N);
  } else {
    // Fallback: atomic scatter (R4-proven correct, slow).
    long long n4 = (long long)out_size / 4;
    int zblocks = (int)((n4 + 255) / 256);
    zero_kernel<<<zblocks, 256, 0, stream>>>((float4*)out, n4);
    long long total_threads = (long long)E * 64;
    int sblocks = (int)((total_threads + 255) / 256);
    scatter_spmm_kernel<<<sblocks, 256, 0, stream>>>(x, rows, cols, vals, out, E, N);
  }

  long long Mtotal = (long long)KCH * N;
  int mblocks = (int)((Mtotal + 31) / 32);
  gemm_relu_inplace<<<mblocks, 256, 0, stream>>>(out, W, Mtotal);
}

// Round 6
// 637.608 us; speedup vs baseline: 8.7339x; 1.0544x over previous
//
#include <hip/hip_runtime.h>

#define KCH 2
#define ZF 128   // Z == F == 128
#define CHUNK 256

// ---------- small utility kernels for the counting sort ----------

__global__ __launch_bounds__(256) void zero_ints(int* __restrict__ p, int n) {
  int i = blockIdx.x * 256 + threadIdx.x;
  if (i < n) p[i] = 0;
}

__global__ __launch_bounds__(256) void hist_kernel(
    const int* __restrict__ rows, int* __restrict__ cnt, int E) {
  int i = blockIdx.x * 256 + threadIdx.x;
  if (i < E) atomicAdd(&cnt[rows[i]], 1);   // 400 KB counter array: L2-resident
}

// Per-chunk (256 counts) reduction -> chunk[b]
__global__ __launch_bounds__(256) void chunk_reduce(
    const int* __restrict__ cnt, int* __restrict__ chunk, int N) {
  __shared__ int s[256];
  int tid = threadIdx.x;
  int i = blockIdx.x * 256 + tid;
  s[tid] = (i < N) ? cnt[i] : 0;
  __syncthreads();
#pragma unroll
  for (int o = 128; o > 0; o >>= 1) {
    if (tid < o) s[tid] += s[tid + o];
    __syncthreads();
  }
  if (tid == 0) chunk[blockIdx.x] = s[0];
}

// Single block: exclusive scan of chunk sums (nch <= 512); also row_off[N]=E.
__global__ __launch_bounds__(512) void chunk_scan(
    int* __restrict__ chunk, int nch, int* __restrict__ row_off, int N, int E) {
  __shared__ int s[512];
  int tid = threadIdx.x;
  int v = (tid < nch) ? chunk[tid] : 0;
  s[tid] = v;
  __syncthreads();
#pragma unroll
  for (int o = 1; o < 512; o <<= 1) {
    int t = (tid >= o) ? s[tid - o] : 0;
    __syncthreads();
    s[tid] += t;
    __syncthreads();
  }
  if (tid < nch) chunk[tid] = s[tid] - v;   // exclusive
  if (tid == 0) row_off[N] = E;
}

// Exclusive scan within each 256-chunk, + chunk base -> row_off[i]
__global__ __launch_bounds__(256) void scan_within_chunk(
    const int* __restrict__ cnt, const int* __restrict__ chunk,
    int* __restrict__ row_off, int N) {
  __shared__ int s[256];
  int tid = threadIdx.x;
  int i = blockIdx.x * 256 + tid;
  int v = (i < N) ? cnt[i] : 0;
  s[tid] = v;
  __syncthreads();
#pragma unroll
  for (int o = 1; o < 256; o <<= 1) {
    int t = (tid >= o) ? s[tid - o] : 0;
    __syncthreads();
    s[tid] += t;
    __syncthreads();
  }
  if (i < N) row_off[i] = chunk[blockIdx.x] + s[tid] - v;
}

// Scatter edges into row-sorted order as packed (col, val) int2 pairs.
__global__ __launch_bounds__(256) void bucket_kernel(
    const int* __restrict__ rows, const int* __restrict__ cols,
    const float* __restrict__ vals, const int* __restrict__ row_off,
    int* __restrict__ cursor, int2* __restrict__ pairs, int E) {
  int i = blockIdx.x * 256 + threadIdx.x;
  if (i >= E) return;
  int r = rows[i];
  int p = row_off[r] + atomicAdd(&cursor[r], 1);
  int2 pr;
  pr.x = cols[i];
  pr.y = __float_as_int(vals[i]);
  pairs[p] = pr;   // one 8B store instead of two scattered 4B stores
}

// ---------- CSR SpMM: one wave per row, lanes 0-31 ch0 / 32-63 ch1 ----------
// Per edge: one float4/lane gather (1KB/wave), 4x unrolled for MLP.
__global__ __launch_bounds__(256) void spmm_csr(
    const float* __restrict__ x, const int* __restrict__ row_off,
    const int2* __restrict__ pairs, float* __restrict__ out, int N) {
  int r = blockIdx.x * 4 + (threadIdx.x >> 6);
  int lane = threadIdx.x & 63;
  if (r >= N) return;
  int k = lane >> 5;
  int g = lane & 31;
  int beg = row_off[r];
  int end = row_off[r + 1];
  const float* xb = x + (size_t)k * N * ZF;   // channel base

  float4 acc = make_float4(0.f, 0.f, 0.f, 0.f);
  int j = beg;
  for (; j + 4 <= end; j += 4) {
    int2 p0 = pairs[j + 0];
    int2 p1 = pairs[j + 1];
    int2 p2 = pairs[j + 2];
    int2 p3 = pairs[j + 3];
    float4 a0 = ((const float4*)(xb + (size_t)p0.x * ZF))[g];
    float4 a1 = ((const float4*)(xb + (size_t)p1.x * ZF))[g];
    float4 a2 = ((const float4*)(xb + (size_t)p2.x * ZF))[g];
    float4 a3 = ((const float4*)(xb + (size_t)p3.x * ZF))[g];
    float v0 = __int_as_float(p0.y);
    float v1 = __int_as_float(p1.y);
    float v2 = __int_as_float(p2.y);
    float v3 = __int_as_float(p3.y);
    acc.x = fmaf(v0, a0.x, acc.x);
    acc.y = fmaf(v0, a0.y, acc.y);
    acc.z = fmaf(v0, a0.z, acc.z);
    acc.w = fmaf(v0, a0.w, acc.w);
    acc.x = fmaf(v1, a1.x, acc.x);
    acc.y = fmaf(v1, a1.y, acc.y);
    acc.z = fmaf(v1, a1.z, acc.z);
    acc.w = fmaf(v1, a1.w, acc.w);
    acc.x = fmaf(v2, a2.x, acc.x);
    acc.y = fmaf(v2, a2.y, acc.y);
    acc.z = fmaf(v2, a2.z, acc.z);
    acc.w = fmaf(v2, a2.w, acc.w);
    acc.x = fmaf(v3, a3.x, acc.x);
    acc.y = fmaf(v3, a3.y, acc.y);
    acc.z = fmaf(v3, a3.z, acc.z);
    acc.w = fmaf(v3, a3.w, acc.w);
  }
  for (; j < end; ++j) {
    int2 p = pairs[j];
    float4 a = ((const float4*)(xb + (size_t)p.x * ZF))[g];
    float v = __int_as_float(p.y);
    acc.x = fmaf(v, a.x, acc.x);
    acc.y = fmaf(v, a.y, acc.y);
    acc.z = fmaf(v, a.z, acc.z);
    acc.w = fmaf(v, a.w, acc.w);
  }
  ((float4*)(out + ((size_t)k * N + (size_t)r) * ZF))[g] = acc;
}

// ---------- fallback path (atomic scatter), used only if ws too small ----------
__device__ inline void atomic_add_f32(float* p, float v) {
#if defined(__HIP_DEVICE_COMPILE__) && defined(__AMDGCN__)
  unsafeAtomicAdd(p, v);
#else
  atomicAdd(p, v);
#endif
}

__global__ __launch_bounds__(256) void zero_kernel(float4* __restrict__ p, long long n4) {
  long long i = (long long)blockIdx.x * 256 + threadIdx.x;
  long long stride = (long long)gridDim.x * 256;
  for (; i < n4; i += stride) p[i] = make_float4(0.f, 0.f, 0.f, 0.f);
}

__global__ __launch_bounds__(256) void scatter_spmm_kernel(
    const float* __restrict__ x, const int* __restrict__ rows,
    const int* __restrict__ cols, const float* __restrict__ vals,
    float* __restrict__ tmp, int E, int N) {
  int t = blockIdx.x * 256 + threadIdx.x;
  int e = t >> 6;
  if (e >= E) return;
  int sub = t & 63;
  int k = sub >> 5;
  int g = sub & 31;
  int row = rows[e];
  int col = cols[e];
  float val = vals[e];
  const float4* src = (const float4*)(x + ((size_t)k * N + col) * ZF);
  float4 v = src[g];
  float* dst = tmp + ((size_t)k * N + row) * ZF + (size_t)g * 4;
  atomic_add_f32(dst + 0, val * v.x);
  atomic_add_f32(dst + 1, val * v.y);
  atomic_add_f32(dst + 2, val * v.z);
  atomic_add_f32(dst + 3, val * v.w);
}

// ---------- Pass 2: io[m,:] = relu(io[m,:] @ W) in place ----------
__global__ __launch_bounds__(256) void gemm_relu_inplace(
    float* __restrict__ io, const float* __restrict__ W, long long Mtotal) {
  __shared__ float Ws[64 * ZF];   // 32 KB (half of W)
  __shared__ float Xs[32 * ZF];   // 16 KB
  int tid = threadIdx.x;
  long long row0 = (long long)blockIdx.x * 32;

  const float4* src = (const float4*)(io + row0 * ZF);
  float4* Xs4 = (float4*)Xs;
#pragma unroll
  for (int i = 0; i < 4; ++i) {
    int idx = tid + i * 256;
    long long r = row0 + (idx >> 5);
    Xs4[idx] = (r < Mtotal) ? src[idx] : make_float4(0.f, 0.f, 0.f, 0.f);
  }

  int f0 = (tid & 31) * 4;
  int rg = tid >> 5;

  float acc[4][4];
#pragma unroll
  for (int j = 0; j < 4; ++j)
#pragma unroll
    for (int i = 0; i < 4; ++i) acc[j][i] = 0.f;

  const float4* W4 = (const float4*)W;
  float4* Ws4 = (float4*)Ws;

  for (int zh = 0; zh < 2; ++zh) {
    __syncthreads();
#pragma unroll
    for (int i = 0; i < 8; ++i) {
      int idx = tid + i * 256;
      Ws4[idx] = W4[(size_t)zh * 2048 + idx];
    }
    __syncthreads();

#pragma unroll 4
    for (int z = 0; z < 64; ++z) {
      float4 wv = *(const float4*)(Ws + z * ZF + f0);
#pragma unroll
      for (int j = 0; j < 4; ++j) {
        float xv = Xs[(rg + 8 * j) * ZF + (zh * 64 + z)];
        acc[j][0] = fmaf(xv, wv.x, acc[j][0]);
        acc[j][1] = fmaf(xv, wv.y, acc[j][1]);
        acc[j][2] = fmaf(xv, wv.z, acc[j][2]);
        acc[j][3] = fmaf(xv, wv.w, acc[j][3]);
      }
    }
  }

#pragma unroll
  for (int j = 0; j < 4; ++j) {
    long long r = row0 + rg + 8 * j;
    if (r < Mtotal) {
      float4 o;
      o.x = fmaxf(acc[j][0], 0.f);
      o.y = fmaxf(acc[j][1], 0.f);
      o.z = fmaxf(acc[j][2], 0.f);
      o.w = fmaxf(acc[j][3], 0.f);
      *(float4*)(io + r * ZF + f0) = o;
    }
  }
}

extern "C" void kernel_launch(void* const* d_in, const int* in_sizes, int n_in,
                              void* d_out, int out_size, void* d_ws, size_t ws_size,
                              hipStream_t stream) {
  const float* x    = (const float*)d_in[0];   // [K, N, Z]
  const int*   rows = (const int*)d_in[1];     // [E]
  const int*   cols = (const int*)d_in[2];     // [E]
  const float* vals = (const float*)d_in[3];   // [E]
  const float* W    = (const float*)d_in[4];   // [Z, F]

  int E = in_sizes[1];
  int N = in_sizes[0] / (KCH * ZF);
  float* out = (float*)d_out;

  int nch = (N + CHUNK - 1) / CHUNK;           // 391 for N=100k (must be <= 512)

  // ws carve-up (16B-aligned blocks)
  size_t off = 0;
  auto carve = [&](size_t bytes) {
    size_t p = off;
    off += (bytes + 15) & ~(size_t)15;
    return (char*)d_ws + p;
  };
  int*  row_off = (int*)carve((size_t)(N + 1) * 4);
  int*  cursor  = (int*)carve((size_t)N * 4);
  int*  chunk   = (int*)carve((size_t)nch * 4);
  int2* pairs   = (int2*)carve((size_t)E * 8);
  bool ws_ok = (off <= ws_size) && (nch <= 512);

  if (ws_ok) {
    int nb_N = (N + 255) / 256;
    int nb_E = (E + 255) / 256;

    zero_ints<<<nb_N, 256, 0, stream>>>(cursor, N);
    hist_kernel<<<nb_E, 256, 0, stream>>>(rows, cursor, E);
    chunk_reduce<<<nch, 256, 0, stream>>>(cursor, chunk, N);
    chunk_scan<<<1, 512, 0, stream>>>(chunk, nch, row_off, N, E);
    scan_within_chunk<<<nch, 256, 0, stream>>>(cursor, chunk, row_off, N);
    zero_ints<<<nb_N, 256, 0, stream>>>(cursor, N);
    bucket_kernel<<<nb_E, 256, 0, stream>>>(rows, cols, vals, row_off, cursor,
                                            pairs, E);
    // CSR SpMM writes every output row exactly once -> no d_out zeroing needed.
    int sblocks = (N + 3) / 4;
    spmm_csr<<<sblocks, 256, 0, stream>>>(x, row_off, pairs, out, N);
  } else {
    // Fallback: atomic scatter (R4-proven correct, slow).
    long long n4 = (long long)out_size / 4;
    int zblocks = (int)((n4 + 255) / 256);
    zero_kernel<<<zblocks, 256, 0, stream>>>((float4*)out, n4);
    long long total_threads = (long long)E * 64;
    int sblocks = (int)((total_threads + 255) / 256);
    scatter_spmm_kernel<<<sblocks, 256, 0, stream>>>(x, rows, cols, vals, out, E, N);
  }

  long long Mtotal = (long long)KCH * N;
  int mblocks = (int)((Mtotal + 31) / 32);
  gemm_relu_inplace<<<mblocks, 256, 0, stream>>>(out, W, Mtotal);
}

// Round 7
// 598.492 us; speedup vs baseline: 9.3047x; 1.0654x over previous
//
#include <hip/hip_runtime.h>

#define KCH 2
#define ZF 128   // Z == F == 128
#define CHUNK 256
typedef unsigned short u16;

// ---------- bf16 helpers ----------
__device__ inline u16 f2bf(float f) {            // round-to-nearest-even
  unsigned u = __float_as_uint(f);
  return (u16)((u + 0x7FFF + ((u >> 16) & 1)) >> 16);
}
__device__ inline float bf2f(u16 h) { return __uint_as_float((unsigned)h << 16); }

// ---------- counting-sort utilities ----------
__global__ __launch_bounds__(256) void zero_ints(int* __restrict__ p, int n) {
  int i = blockIdx.x * 256 + threadIdx.x;
  if (i < n) p[i] = 0;
}

__global__ __launch_bounds__(256) void hist_kernel(
    const int* __restrict__ rows, int* __restrict__ cnt, int E) {
  int i = blockIdx.x * 256 + threadIdx.x;
  if (i < E) atomicAdd(&cnt[rows[i]], 1);   // 400 KB counter array: L2-resident
}

__global__ __launch_bounds__(256) void chunk_reduce(
    const int* __restrict__ cnt, int* __restrict__ chunk, int N) {
  __shared__ int s[256];
  int tid = threadIdx.x;
  int i = blockIdx.x * 256 + tid;
  s[tid] = (i < N) ? cnt[i] : 0;
  __syncthreads();
#pragma unroll
  for (int o = 128; o > 0; o >>= 1) {
    if (tid < o) s[tid] += s[tid + o];
    __syncthreads();
  }
  if (tid == 0) chunk[blockIdx.x] = s[0];
}

__global__ __launch_bounds__(512) void chunk_scan(
    int* __restrict__ chunk, int nch, int* __restrict__ row_off, int N, int E) {
  __shared__ int s[512];
  int tid = threadIdx.x;
  int v = (tid < nch) ? chunk[tid] : 0;
  s[tid] = v;
  __syncthreads();
#pragma unroll
  for (int o = 1; o < 512; o <<= 1) {
    int t = (tid >= o) ? s[tid - o] : 0;
    __syncthreads();
    s[tid] += t;
    __syncthreads();
  }
  if (tid < nch) chunk[tid] = s[tid] - v;   // exclusive
  if (tid == 0) row_off[N] = E;
}

// Exclusive scan within each 256-chunk; writes row_off AND seeds cursor.
__global__ __launch_bounds__(256) void scan_within_chunk(
    const int* __restrict__ cnt, const int* __restrict__ chunk,
    int* __restrict__ row_off, int* __restrict__ cursor, int N) {
  __shared__ int s[256];
  int tid = threadIdx.x;
  int i = blockIdx.x * 256 + tid;
  int v = (i < N) ? cnt[i] : 0;
  s[tid] = v;
  __syncthreads();
#pragma unroll
  for (int o = 1; o < 256; o <<= 1) {
    int t = (tid >= o) ? s[tid - o] : 0;
    __syncthreads();
    s[tid] += t;
    __syncthreads();
  }
  if (i < N) {
    int start = chunk[blockIdx.x] + s[tid] - v;
    row_off[i] = start;
    cursor[i] = start;   // bucket uses cursor directly (no row_off gather)
  }
}

// Scatter edges into row-sorted order as packed (col, val) int2 pairs.
__global__ __launch_bounds__(256) void bucket_kernel(
    const int* __restrict__ rows, const int* __restrict__ cols,
    const float* __restrict__ vals, int* __restrict__ cursor,
    int2* __restrict__ pairs, int E) {
  int i = blockIdx.x * 256 + threadIdx.x;
  if (i >= E) return;
  int r = rows[i];
  int p = atomicAdd(&cursor[r], 1);
  int2 pr;
  pr.x = cols[i];
  pr.y = __float_as_int(vals[i]);
  pairs[p] = pr;
}

// ---------- x -> bf16, channel-interleaved: xi[node][k][z] ----------
__global__ __launch_bounds__(256) void convert_x(
    const float* __restrict__ x, u16* __restrict__ xi, int N) {
  int t = blockIdx.x * 256 + threadIdx.x;
  int n = t >> 6;
  if (n >= N) return;
  int lane = t & 63;          // k = lane>>5, z4 = lane&31
  int k = lane >> 5;
  int z4 = lane & 31;
  float4 v = ((const float4*)(x + ((size_t)k * N + n) * ZF))[z4];
  ushort4 o;
  o.x = f2bf(v.x);
  o.y = f2bf(v.y);
  o.z = f2bf(v.z);
  o.w = f2bf(v.w);
  ((ushort4*)(xi + (size_t)n * 256))[lane] = o;   // 512 B contiguous per node
}

// ---------- CSR SpMM over bf16 x: one wave per row, one 512B gather/edge ----------
__global__ __launch_bounds__(256) void spmm_csr_bf16(
    const u16* __restrict__ xi, const int* __restrict__ row_off,
    const int2* __restrict__ pairs, float* __restrict__ out, int N) {
  int r = blockIdx.x * 4 + (threadIdx.x >> 6);
  int lane = threadIdx.x & 63;
  if (r >= N) return;
  int beg = row_off[r];
  int end = row_off[r + 1];

  float4 acc = make_float4(0.f, 0.f, 0.f, 0.f);
  int j = beg;
  for (; j + 4 <= end; j += 4) {
    int2 p0 = pairs[j + 0];
    int2 p1 = pairs[j + 1];
    int2 p2 = pairs[j + 2];
    int2 p3 = pairs[j + 3];
    ushort4 a0 = ((const ushort4*)(xi + (size_t)p0.x * 256))[lane];
    ushort4 a1 = ((const ushort4*)(xi + (size_t)p1.x * 256))[lane];
    ushort4 a2 = ((const ushort4*)(xi + (size_t)p2.x * 256))[lane];
    ushort4 a3 = ((const ushort4*)(xi + (size_t)p3.x * 256))[lane];
    float v0 = __int_as_float(p0.y);
    float v1 = __int_as_float(p1.y);
    float v2 = __int_as_float(p2.y);
    float v3 = __int_as_float(p3.y);
    acc.x = fmaf(v0, bf2f(a0.x), acc.x);
    acc.y = fmaf(v0, bf2f(a0.y), acc.y);
    acc.z = fmaf(v0, bf2f(a0.z), acc.z);
    acc.w = fmaf(v0, bf2f(a0.w), acc.w);
    acc.x = fmaf(v1, bf2f(a1.x), acc.x);
    acc.y = fmaf(v1, bf2f(a1.y), acc.y);
    acc.z = fmaf(v1, bf2f(a1.z), acc.z);
    acc.w = fmaf(v1, bf2f(a1.w), acc.w);
    acc.x = fmaf(v2, bf2f(a2.x), acc.x);
    acc.y = fmaf(v2, bf2f(a2.y), acc.y);
    acc.z = fmaf(v2, bf2f(a2.z), acc.z);
    acc.w = fmaf(v2, bf2f(a2.w), acc.w);
    acc.x = fmaf(v3, bf2f(a3.x), acc.x);
    acc.y = fmaf(v3, bf2f(a3.y), acc.y);
    acc.z = fmaf(v3, bf2f(a3.z), acc.z);
    acc.w = fmaf(v3, bf2f(a3.w), acc.w);
  }
  for (; j < end; ++j) {
    int2 p = pairs[j];
    ushort4 a = ((const ushort4*)(xi + (size_t)p.x * 256))[lane];
    float v = __int_as_float(p.y);
    acc.x = fmaf(v, bf2f(a.x), acc.x);
    acc.y = fmaf(v, bf2f(a.y), acc.y);
    acc.z = fmaf(v, bf2f(a.z), acc.z);
    acc.w = fmaf(v, bf2f(a.w), acc.w);
  }
  int k = lane >> 5;
  int g = lane & 31;
  ((float4*)(out + ((size_t)k * N + (size_t)r) * ZF))[g] = acc;
}

// ---------- mid-tier fallback: fp32 CSR SpMM (R6-proven) ----------
__global__ __launch_bounds__(256) void spmm_csr(
    const float* __restrict__ x, const int* __restrict__ row_off,
    const int2* __restrict__ pairs, float* __restrict__ out, int N) {
  int r = blockIdx.x * 4 + (threadIdx.x >> 6);
  int lane = threadIdx.x & 63;
  if (r >= N) return;
  int k = lane >> 5;
  int g = lane & 31;
  int beg = row_off[r];
  int end = row_off[r + 1];
  const float* xb = x + (size_t)k * N * ZF;
  float4 acc = make_float4(0.f, 0.f, 0.f, 0.f);
  for (int j = beg; j < end; ++j) {
    int2 p = pairs[j];
    float4 a = ((const float4*)(xb + (size_t)p.x * ZF))[g];
    float v = __int_as_float(p.y);
    acc.x = fmaf(v, a.x, acc.x);
    acc.y = fmaf(v, a.y, acc.y);
    acc.z = fmaf(v, a.z, acc.z);
    acc.w = fmaf(v, a.w, acc.w);
  }
  ((float4*)(out + ((size_t)k * N + (size_t)r) * ZF))[g] = acc;
}

// ---------- last-resort fallback: atomic scatter ----------
__device__ inline void atomic_add_f32(float* p, float v) {
#if defined(__HIP_DEVICE_COMPILE__) && defined(__AMDGCN__)
  unsafeAtomicAdd(p, v);
#else
  atomicAdd(p, v);
#endif
}

__global__ __launch_bounds__(256) void zero_kernel(float4* __restrict__ p, long long n4) {
  long long i = (long long)blockIdx.x * 256 + threadIdx.x;
  long long stride = (long long)gridDim.x * 256;
  for (; i < n4; i += stride) p[i] = make_float4(0.f, 0.f, 0.f, 0.f);
}

__global__ __launch_bounds__(256) void scatter_spmm_kernel(
    const float* __restrict__ x, const int* __restrict__ rows,
    const int* __restrict__ cols, const float* __restrict__ vals,
    float* __restrict__ tmp, int E, int N) {
  int t = blockIdx.x * 256 + threadIdx.x;
  int e = t >> 6;
  if (e >= E) return;
  int sub = t & 63;
  int k = sub >> 5;
  int g = sub & 31;
  int row = rows[e];
  int col = cols[e];
  float val = vals[e];
  const float4* src = (const float4*)(x + ((size_t)k * N + col) * ZF);
  float4 v = src[g];
  float* dst = tmp + ((size_t)k * N + row) * ZF + (size_t)g * 4;
  atomic_add_f32(dst + 0, val * v.x);
  atomic_add_f32(dst + 1, val * v.y);
  atomic_add_f32(dst + 2, val * v.z);
  atomic_add_f32(dst + 3, val * v.w);
}

// ---------- Pass 2: io[m,:] = relu(io[m,:] @ W) in place ----------
__global__ __launch_bounds__(256) void gemm_relu_inplace(
    float* __restrict__ io, const float* __restrict__ W, long long Mtotal) {
  __shared__ float Ws[64 * ZF];   // 32 KB (half of W)
  __shared__ float Xs[32 * ZF];   // 16 KB
  int tid = threadIdx.x;
  long long row0 = (long long)blockIdx.x * 32;

  const float4* src = (const float4*)(io + row0 * ZF);
  float4* Xs4 = (float4*)Xs;
#pragma unroll
  for (int i = 0; i < 4; ++i) {
    int idx = tid + i * 256;
    long long r = row0 + (idx >> 5);
    Xs4[idx] = (r < Mtotal) ? src[idx] : make_float4(0.f, 0.f, 0.f, 0.f);
  }

  int f0 = (tid & 31) * 4;
  int rg = tid >> 5;

  float acc[4][4];
#pragma unroll
  for (int j = 0; j < 4; ++j)
#pragma unroll
    for (int i = 0; i < 4; ++i) acc[j][i] = 0.f;

  const float4* W4 = (const float4*)W;
  float4* Ws4 = (float4*)Ws;

  for (int zh = 0; zh < 2; ++zh) {
    __syncthreads();
#pragma unroll
    for (int i = 0; i < 8; ++i) {
      int idx = tid + i * 256;
      Ws4[idx] = W4[(size_t)zh * 2048 + idx];
    }
    __syncthreads();

#pragma unroll 4
    for (int z = 0; z < 64; ++z) {
      float4 wv = *(const float4*)(Ws + z * ZF + f0);
#pragma unroll
      for (int j = 0; j < 4; ++j) {
        float xv = Xs[(rg + 8 * j) * ZF + (zh * 64 + z)];
        acc[j][0] = fmaf(xv, wv.x, acc[j][0]);
        acc[j][1] = fmaf(xv, wv.y, acc[j][1]);
        acc[j][2] = fmaf(xv, wv.z, acc[j][2]);
        acc[j][3] = fmaf(xv, wv.w, acc[j][3]);
      }
    }
  }

#pragma unroll
  for (int j = 0; j < 4; ++j) {
    long long r = row0 + rg + 8 * j;
    if (r < Mtotal) {
      float4 o;
      o.x = fmaxf(acc[j][0], 0.f);
      o.y = fmaxf(acc[j][1], 0.f);
      o.z = fmaxf(acc[j][2], 0.f);
      o.w = fmaxf(acc[j][3], 0.f);
      *(float4*)(io + r * ZF + f0) = o;
    }
  }
}

extern "C" void kernel_launch(void* const* d_in, const int* in_sizes, int n_in,
                              void* d_out, int out_size, void* d_ws, size_t ws_size,
                              hipStream_t stream) {
  const float* x    = (const float*)d_in[0];   // [K, N, Z]
  const int*   rows = (const int*)d_in[1];     // [E]
  const int*   cols = (const int*)d_in[2];     // [E]
  const float* vals = (const float*)d_in[3];   // [E]
  const float* W    = (const float*)d_in[4];   // [Z, F]

  int E = in_sizes[1];
  int N = in_sizes[0] / (KCH * ZF);
  float* out = (float*)d_out;

  int nch = (N + CHUNK - 1) / CHUNK;           // 391 for N=100k (must be <= 512)

  size_t off = 0;
  auto carve = [&](size_t bytes) {
    size_t p = off;
    off += (bytes + 15) & ~(size_t)15;
    return (char*)d_ws + p;
  };
  int*  row_off = (int*)carve((size_t)(N + 1) * 4);
  int*  cursor  = (int*)carve((size_t)N * 4);
  int*  chunk   = (int*)carve((size_t)nch * 4);
  int2* pairs   = (int2*)carve((size_t)E * 8);
  size_t off_csr = off;
  u16*  xi      = (u16*)carve((size_t)N * KCH * ZF * 2);   // 51.2 MB

  bool csr_ok  = (off_csr <= ws_size) && (nch <= 512);
  bool bf16_ok = (off <= ws_size) && (nch <= 512);

  if (csr_ok) {
    int nb_N = (N + 255) / 256;
    int nb_E = (E + 255) / 256;

    zero_ints<<<nb_N, 256, 0, stream>>>(cursor, N);
    hist_kernel<<<nb_E, 256, 0, stream>>>(rows, cursor, E);
    chunk_reduce<<<nch, 256, 0, stream>>>(cursor, chunk, N);
    chunk_scan<<<1, 512, 0, stream>>>(chunk, nch, row_off, N, E);
    scan_within_chunk<<<nch, 256, 0, stream>>>(cursor, chunk, row_off, cursor, N);
    bucket_kernel<<<nb_E, 256, 0, stream>>>(rows, cols, vals, cursor, pairs, E);

    int sblocks = (N + 3) / 4;
    if (bf16_ok) {
      int cblocks = (int)(((size_t)N * 64 + 255) / 256);
      convert_x<<<cblocks, 256, 0, stream>>>(x, xi, N);
      spmm_csr_bf16<<<sblocks, 256, 0, stream>>>(xi, row_off, pairs, out, N);
    } else {
      spmm_csr<<<sblocks, 256, 0, stream>>>(x, row_off, pairs, out, N);
    }
  } else {
    long long n4 = (long long)out_size / 4;
    int zblocks = (int)((n4 + 255) / 256);
    zero_kernel<<<zblocks, 256, 0, stream>>>((float4*)out, n4);
    long long total_threads = (long long)E * 64;
    int sblocks = (int)((total_threads + 255) / 256);
    scatter_spmm_kernel<<<sblocks, 256, 0, stream>>>(x, rows, cols, vals, out, E, N);
  }

  long long Mtotal = (long long)KCH * N;
  int mblocks = (int)((Mtotal + 31) / 32);
  gemm_relu_inplace<<<mblocks, 256, 0, stream>>>(out, W, Mtotal);
}